// Round 1
// baseline (330.643 us; speedup 1.0000x reference)
//
#include <hip/hip_runtime.h>

// PointSample: bilinear grid_sample, align_corners=False, border clamp.
// features: [B=8, H=256, W=256, C=128] fp32 channels-last
// grid:     [B=8, P=8192, 2] fp32 (x, y) in [0, 1]
// out:      [B, P, C] fp32
//
// V2 changes vs 330.7 µs baseline:
//  - 2 points per thread: 8 independent corner gathers issued before any use
//    (doubles per-wave outstanding VMEM; kernel is latency-bound at ~8% HBM BW).
//  - 32-bit element indices (all byte offsets < 2^28) so loads use the
//    saddr + 32-bit voffset form: 1 VGPR per address instead of a 64-bit pair.
//  - non-temporal output stores: out is write-once, keep L2/L3 for features.
// Mapping unchanged otherwise: 32 consecutive lanes = one point's 128 channels
// as float4 -> every corner gather is a coalesced 512 B contiguous read.

constexpr int B = 8, H = 256, W = 256, C = 128, P = 8192;
constexpr int C4 = C / 4;           // 32 float4 chunks per point
constexpr int LOG2_C4 = 5;
constexpr int LOG2_P  = 13;         // P = 8192
constexpr int BP      = B * P;      // 65536 points
constexpr int NPT     = 2;          // points per thread
constexpr int HALFPTS = BP / NPT;   // 32768

typedef float v4f __attribute__((ext_vector_type(4)));

struct Samp {
    int   i00, i01, i10, i11;       // float4 indices of the 4 corner reads
    float w00, w01, w10, w11;       // bilinear weights
};

__device__ __forceinline__ Samp make_samp(const float2 g, const int pg, const int c4)
{
    const int b = pg >> LOG2_P;
    // mirror reference expression order exactly (verified numerics)
    const float x = g.x * 2.0f - 1.0f;
    const float y = g.y * 2.0f - 1.0f;
    const float ix = ((x + 1.0f) * (float)W - 1.0f) * 0.5f;
    const float iy = ((y + 1.0f) * (float)H - 1.0f) * 0.5f;
    const float x0f = floorf(ix);
    const float y0f = floorf(iy);
    const float wx = ix - x0f;
    const float wy = iy - y0f;
    const int xi = (int)x0f;
    const int yi = (int)y0f;
    const int x0 = min(max(xi,     0), W - 1);
    const int x1 = min(max(xi + 1, 0), W - 1);
    const int y0 = min(max(yi,     0), H - 1);
    const int y1 = min(max(yi + 1, 0), H - 1);

    Samp s;
    const int fb = (b << 21) + c4;          // b * H*W*C4 + c4  (max 2^24, fits int)
    const int r0 = fb + y0 * (W * C4);
    const int r1 = fb + y1 * (W * C4);
    s.i00 = r0 + x0 * C4;
    s.i01 = r0 + x1 * C4;
    s.i10 = r1 + x0 * C4;
    s.i11 = r1 + x1 * C4;
    s.w00 = (1.0f - wy) * (1.0f - wx);
    s.w01 = (1.0f - wy) * wx;
    s.w10 = wy * (1.0f - wx);
    s.w11 = wy * wx;
    return s;
}

__device__ __forceinline__ v4f blend(const float4 c00, const float4 c01,
                                     const float4 c10, const float4 c11,
                                     const float w00, const float w01,
                                     const float w10, const float w11)
{
    v4f o;
    o.x = c00.x * w00 + c01.x * w01 + c10.x * w10 + c11.x * w11;
    o.y = c00.y * w00 + c01.y * w01 + c10.y * w10 + c11.y * w11;
    o.z = c00.z * w00 + c01.z * w01 + c10.z * w10 + c11.z * w11;
    o.w = c00.w * w00 + c01.w * w01 + c10.w * w10 + c11.w * w11;
    return o;
}

__global__ __launch_bounds__(256) void pointsample_kernel(
    const float4* __restrict__ feat,   // [B*H*W*C4] float4
    const float2* __restrict__ grid,   // [B*P] (x,y)
    v4f*          __restrict__ out)    // [B*P*C4]
{
    const int t   = blockIdx.x * blockDim.x + threadIdx.x;
    const int c4  = t & (C4 - 1);       // channel-quad index 0..31
    const int q   = t >> LOG2_C4;       // 0..HALFPTS-1
    const int pgA = q;                  // first point
    const int pgB = q + HALFPTS;        // second point (disjoint half)

    const float2 gA = grid[pgA];
    const float2 gB = grid[pgB];
    const Samp sA = make_samp(gA, pgA, c4);
    const Samp sB = make_samp(gB, pgB, c4);

    // Issue all 8 independent corner gathers before any use -> 8 outstanding
    // VMEM loads per thread covering the full miss latency.
    const float4 a00 = feat[sA.i00];
    const float4 a01 = feat[sA.i01];
    const float4 a10 = feat[sA.i10];
    const float4 a11 = feat[sA.i11];
    const float4 b00 = feat[sB.i00];
    const float4 b01 = feat[sB.i01];
    const float4 b10 = feat[sB.i10];
    const float4 b11 = feat[sB.i11];

    const v4f oA = blend(a00, a01, a10, a11, sA.w00, sA.w01, sA.w10, sA.w11);
    const v4f oB = blend(b00, b01, b10, b11, sB.w00, sB.w01, sB.w10, sB.w11);

    // Non-temporal: output is streamed once, never re-read -> keep L2 for feat.
    __builtin_nontemporal_store(oA, out + (pgA << LOG2_C4) + c4);
    __builtin_nontemporal_store(oB, out + (pgB << LOG2_C4) + c4);
}

extern "C" void kernel_launch(void* const* d_in, const int* in_sizes, int n_in,
                              void* d_out, int out_size, void* d_ws, size_t ws_size,
                              hipStream_t stream) {
    const float4* feat = (const float4*)d_in[0];
    const float2* grd  = (const float2*)d_in[1];
    v4f*          out  = (v4f*)d_out;

    constexpr int total_threads = BP * C4 / NPT;    // 1,048,576
    constexpr int block = 256;
    constexpr int nblocks = total_threads / block;  // 4096, exact

    pointsample_kernel<<<nblocks, block, 0, stream>>>(feat, grd, out);
}